// Round 1
// baseline (849.652 us; speedup 1.0000x reference)
//
#include <hip/hip_runtime.h>
#include <hip/hip_bf16.h>
#include <math.h>

#define BB 8
#define FH 8
#define NN 2048
#define TIN 5
#define H1 32
#define H2 64
#define NEGV (-9.0e15f)

typedef const void* cvp;

__device__ __forceinline__ float ldx(cvp p, int i, int bf) {
  if (bf) return __bfloat162float(((const __hip_bfloat16*)p)[i]);
  return ((const float*)p)[i];
}

// ---------------------------------------------------------------- detector
// bf16 data: low 16 bits of each word are a bf16 value -> exponent field
// ((w>>7)&0xFF) clusters in ~[110,127]. fp32 data: those bits are random
// mantissa bits -> ~20% fall in [100,150]. Count over 1024 words.
__global__ void k_detect(const unsigned int* __restrict__ w, int* __restrict__ flag) {
  __shared__ int cnt;
  if (threadIdx.x == 0) cnt = 0;
  __syncthreads();
  int local = 0;
  for (int i = threadIdx.x; i < 1024; i += 256) {
    unsigned e = (w[i] >> 7) & 0xFFu;
    local += (e >= 100u && e <= 150u) ? 1 : 0;
  }
  atomicAdd(&cnt, local);
  __syncthreads();
  if (threadIdx.x == 0) *flag = (cnt > 700) ? 1 : 0;
}

// ---------------------------------------------------------------- h1 = elu(x @ W1^T + b1)
// x[b,n,ti*FH+f] = hist[b,f,n,ti]
__global__ void k_h1(cvp hist, cvp W1, cvp b1, float* __restrict__ h1,
                     const int* __restrict__ flagp) {
  __shared__ float w[H1 * TIN * FH];
  __shared__ float bb[H1];
  int bf = *flagp;
  int tid = threadIdx.x;
  for (int i = tid; i < H1 * TIN * FH; i += 256) w[i] = ldx(W1, i, bf);
  if (tid < H1) bb[tid] = ldx(b1, tid, bf);
  __syncthreads();
  int t = blockIdx.x >> 8;
  int n = ((blockIdx.x & 255) << 3) + (tid >> 5);
  int k = tid & 31;
  float acc = bb[k];
#pragma unroll
  for (int ti = 0; ti < TIN; ++ti) {
#pragma unroll
    for (int f = 0; f < FH; ++f) {
      acc += ldx(hist, (((t * FH + f) * NN + n) * TIN) + ti, bf) *
             w[k * (TIN * FH) + ti * FH + f];
    }
  }
  h1[((t * NN + n) * H1) + k] = (acc > 0.f) ? acc : expm1f(acc);
}

// ---------------------------------------------------------------- LSTM
// wave handles 2 nodes; gate weights in LDS as float4[k][lane] = {i,f,g,o} rows
__global__ __launch_bounds__(256, 1) void k_lstm(
    const float* __restrict__ h1, cvp W_ih, cvp W_hh, cvp b_ih, cvp b_hh,
    float* __restrict__ hs, const int* __restrict__ flagp) {
  __shared__ float4 wih[H1 * 64];   // 32 KB
  __shared__ float4 whh[H2 * 64];   // 64 KB
  __shared__ float4 bsum[64];
  __shared__ float xbuf[4][2][H1];
  __shared__ float hbuf[4][2][H2];
  int bf = *flagp;
  int tid = threadIdx.x;
  for (int idx = tid; idx < 256 * H1; idx += 256) {
    int r = idx >> 5, k = idx & 31;           // r = gate row, k = input idx
    ((float*)wih)[(((k << 6) + (r & 63)) << 2) + (r >> 6)] = ldx(W_ih, idx, bf);
  }
  for (int idx = tid; idx < 256 * H2; idx += 256) {
    int r = idx >> 6, k = idx & 63;
    ((float*)whh)[(((k << 6) + (r & 63)) << 2) + (r >> 6)] = ldx(W_hh, idx, bf);
  }
  {
    int r = tid;
    ((float*)bsum)[((r & 63) << 2) + (r >> 6)] = ldx(b_ih, r, bf) + ldx(b_hh, r, bf);
  }
  int wave = tid >> 6, lane = tid & 63;
  int na = (blockIdx.x << 3) + (wave << 1);
  hbuf[wave][0][lane] = 0.f;
  hbuf[wave][1][lane] = 0.f;
  __syncthreads();
  float4 bs = bsum[lane];
  float c0 = 0.f, c1 = 0.f;
  for (int t = 0; t < BB; ++t) {
    {
      int which = lane >> 5, li = lane & 31;
      xbuf[wave][which][li] = h1[((t * NN + na + which) * H1) + li];
    }
    __syncthreads();
    float ai0 = bs.x, af0 = bs.y, ag0 = bs.z, ao0 = bs.w;
    float ai1 = bs.x, af1 = bs.y, ag1 = bs.z, ao1 = bs.w;
#pragma unroll
    for (int k = 0; k < H1; ++k) {
      float4 wv = wih[(k << 6) + lane];
      float xa = xbuf[wave][0][k], xb = xbuf[wave][1][k];
      ai0 += wv.x * xa; af0 += wv.y * xa; ag0 += wv.z * xa; ao0 += wv.w * xa;
      ai1 += wv.x * xb; af1 += wv.y * xb; ag1 += wv.z * xb; ao1 += wv.w * xb;
    }
#pragma unroll
    for (int k = 0; k < H2; ++k) {
      float4 wv = whh[(k << 6) + lane];
      float ha = hbuf[wave][0][k], hb = hbuf[wave][1][k];
      ai0 += wv.x * ha; af0 += wv.y * ha; ag0 += wv.z * ha; ao0 += wv.w * ha;
      ai1 += wv.x * hb; af1 += wv.y * hb; ag1 += wv.z * hb; ao1 += wv.w * hb;
    }
    float h0v, h1v;
    {
      float si = 1.f / (1.f + __expf(-ai0));
      float sf = 1.f / (1.f + __expf(-af0));
      float so = 1.f / (1.f + __expf(-ao0));
      float tg = tanhf(ag0);
      c0 = sf * c0 + si * tg;
      h0v = so * tanhf(c0);
    }
    {
      float si = 1.f / (1.f + __expf(-ai1));
      float sf = 1.f / (1.f + __expf(-af1));
      float so = 1.f / (1.f + __expf(-ao1));
      float tg = tanhf(ag1);
      c1 = sf * c1 + si * tg;
      h1v = so * tanhf(c1);
    }
    __syncthreads();
    hbuf[wave][0][lane] = h0v;
    hbuf[wave][1][lane] = h1v;
    hs[((t * NN + na) * H2) + lane] = h0v;
    hs[((t * NN + na + 1) * H2) + lane] = h1v;
    __syncthreads();
  }
}

// ---------------------------------------------------------------- Wh = hs@Wg, src/dst projections
__global__ void k_gatprep(const float* __restrict__ hs, cvp Wg, cvp a_src, cvp a_dst,
                          float* __restrict__ Wh, float* __restrict__ sv,
                          float* __restrict__ dv, const int* __restrict__ flagp) {
  __shared__ float wg[H2 * H2];
  int bf = *flagp;
  int tid = threadIdx.x;
  for (int i = tid; i < H2 * H2; i += 256) wg[i] = ldx(Wg, i, bf);
  __syncthreads();
  int wave = tid >> 6, lane = tid & 63;
  int row = (blockIdx.x << 2) + wave;   // [0, B*N)
  float hreg = hs[row * H2 + lane];
  float acc = 0.f;
#pragma unroll
  for (int k = 0; k < H2; ++k) {
    float hk = __shfl(hreg, k, 64);
    acc += hk * wg[(k << 6) + lane];
  }
  Wh[row * H2 + lane] = acc;
  float s = acc * ldx(a_src, lane, bf);
  float d = acc * ldx(a_dst, lane, bf);
#pragma unroll
  for (int off = 32; off > 0; off >>= 1) {
    s += __shfl_xor(s, off, 64);
    d += __shfl_xor(d, off, 64);
  }
  if (lane == 0) { sv[row] = s; dv[row] = d; }
}

// ---------------------------------------------------------------- GAT: masked softmax + aggregate
// block = (b, tile of 8 i-rows). Phase A: weights into LDS. Phase B: wave w
// aggregates rows w and w+4 over all j.
__global__ __launch_bounds__(256) void k_gat(
    const int* __restrict__ adj, const float* __restrict__ Wh,
    const float* __restrict__ sv, const float* __restrict__ dv,
    void* __restrict__ out, const int* __restrict__ flagp) {
  __shared__ __align__(16) float wr[8 * NN];   // 64 KB
  __shared__ float dstb[NN];                   // 8 KB
  __shared__ float red[4];
  __shared__ float invS[8];
  int bf = *flagp;
  int tid = threadIdx.x;
  int wave = tid >> 6, lane = tid & 63;
  int b = blockIdx.x >> 8;
  int i0 = (blockIdx.x & 255) << 3;
  for (int j = tid; j < NN; j += 256) dstb[j] = dv[b * NN + j];
  __syncthreads();
  for (int ii = 0; ii < 8; ++ii) {
    int i = i0 + ii;
    float s = sv[b * NN + i];
    const int* arow = adj + (((size_t)(b * 2 + 1) * NN + i) << 11);
    float ev[8];
    float lmax = NEGV;
#pragma unroll
    for (int k = 0; k < 8; ++k) {
      int j = tid + (k << 8);
      float e = NEGV;
      if (arow[j] != 0) {
        float x = s + dstb[j];
        e = (x > 0.f) ? x : 0.2f * x;
      }
      ev[k] = e;
      lmax = fmaxf(lmax, e);
    }
#pragma unroll
    for (int off = 32; off > 0; off >>= 1) lmax = fmaxf(lmax, __shfl_xor(lmax, off, 64));
    if (lane == 0) red[wave] = lmax;
    __syncthreads();
    float m = fmaxf(fmaxf(red[0], red[1]), fmaxf(red[2], red[3]));
    __syncthreads();
    float lsum = 0.f;
#pragma unroll
    for (int k = 0; k < 8; ++k) {
      int j = tid + (k << 8);
      float p = __expf(ev[k] - m);
      wr[ii * NN + j] = p;
      lsum += p;
    }
#pragma unroll
    for (int off = 32; off > 0; off >>= 1) lsum += __shfl_xor(lsum, off, 64);
    if (lane == 0) red[wave] = lsum;
    __syncthreads();
    if (tid == 0) invS[ii] = 1.f / (red[0] + red[1] + red[2] + red[3]);
    __syncthreads();
  }
  // Phase B
  const float* whb = Wh + (size_t)b * NN * H2;
  float acc0 = 0.f, acc1 = 0.f;
  for (int j = 0; j < NN; j += 4) {
    float4 w0 = *(const float4*)&wr[wave * NN + j];
    float4 w1 = *(const float4*)&wr[(wave + 4) * NN + j];
    float v0 = whb[(j + 0) * H2 + lane];
    float v1 = whb[(j + 1) * H2 + lane];
    float v2 = whb[(j + 2) * H2 + lane];
    float v3 = whb[(j + 3) * H2 + lane];
    acc0 += w0.x * v0 + w0.y * v1 + w0.z * v2 + w0.w * v3;
    acc1 += w1.x * v0 + w1.y * v1 + w1.z * v2 + w1.w * v3;
  }
  float o0 = acc0 * invS[wave];
  float o1 = acc1 * invS[wave + 4];
  o0 = (o0 > 0.f) ? o0 : expm1f(o0);
  o1 = (o1 > 0.f) ? o1 : expm1f(o1);
  size_t base0 = ((size_t)b * NN + (i0 + wave)) * H2 + lane;
  size_t base1 = ((size_t)b * NN + (i0 + wave + 4)) * H2 + lane;
  if (bf) {
    ((__hip_bfloat16*)out)[base0] = __float2bfloat16(o0);
    ((__hip_bfloat16*)out)[base1] = __float2bfloat16(o1);
  } else {
    ((float*)out)[base0] = o0;
    ((float*)out)[base1] = o1;
  }
}

// ---------------------------------------------------------------- launch
extern "C" void kernel_launch(void* const* d_in, const int* in_sizes, int n_in,
                              void* d_out, int out_size, void* d_ws, size_t ws_size,
                              hipStream_t stream) {
  (void)in_sizes; (void)n_in; (void)out_size; (void)ws_size;
  cvp hist  = d_in[0];
  const int* adj = (const int*)d_in[1];
  cvp W1    = d_in[2];
  cvp b1    = d_in[3];
  cvp W_ih  = d_in[4];
  cvp W_hh  = d_in[5];
  cvp b_ih  = d_in[6];
  cvp b_hh  = d_in[7];
  cvp Wg    = d_in[8];
  cvp a_src = d_in[9];
  cvp a_dst = d_in[10];

  float* ws  = (float*)d_ws;
  float* h1  = ws;                       // B*N*H1 = 524288
  float* hs  = h1 + BB * NN * H1;        // B*N*H2 = 1048576
  float* Whp = hs + BB * NN * H2;        // 1048576
  float* sv  = Whp + BB * NN * H2;       // 16384
  float* dv  = sv + BB * NN;             // 16384
  int* flag  = (int*)(dv + BB * NN);

  k_detect<<<1, 256, 0, stream>>>((const unsigned int*)W_ih, flag);
  k_h1<<<2048, 256, 0, stream>>>(hist, W1, b1, h1, flag);
  k_lstm<<<256, 256, 0, stream>>>(h1, W_ih, W_hh, b_ih, b_hh, hs, flag);
  k_gatprep<<<4096, 256, 0, stream>>>(hs, Wg, a_src, a_dst, Whp, sv, dv, flag);
  k_gat<<<2048, 256, 0, stream>>>(adj, Whp, sv, dv, d_out, flag);
}

// Round 2
// 583.313 us; speedup vs baseline: 1.4566x; 1.4566x over previous
//
#include <hip/hip_runtime.h>
#include <hip/hip_bf16.h>
#include <math.h>

#define BB 8
#define FH 8
#define NN 2048
#define TIN 5
#define H1 32
#define H2 64

typedef const void* cvp;
typedef __attribute__((ext_vector_type(8))) short short8;
typedef __attribute__((ext_vector_type(4))) float floatx4;

__device__ __forceinline__ float ldx(cvp p, int i, int bf) {
  if (bf) return __bfloat162float(((const __hip_bfloat16*)p)[i]);
  return ((const float*)p)[i];
}

// ---------------------------------------------------------------- detector
__global__ void k_detect(const unsigned int* __restrict__ w, int* __restrict__ flag) {
  __shared__ int cnt;
  if (threadIdx.x == 0) cnt = 0;
  __syncthreads();
  int local = 0;
  for (int i = threadIdx.x; i < 1024; i += 256) {
    unsigned e = (w[i] >> 7) & 0xFFu;
    local += (e >= 100u && e <= 150u) ? 1 : 0;
  }
  atomicAdd(&cnt, local);
  __syncthreads();
  if (threadIdx.x == 0) *flag = (cnt > 700) ? 1 : 0;
}

// ---------------------------------------------------------------- h1 = elu(x @ W1^T + b1)
__global__ void k_h1(cvp hist, cvp W1, cvp b1, float* __restrict__ h1,
                     const int* __restrict__ flagp) {
  __shared__ float w[H1 * TIN * FH];
  __shared__ float bb[H1];
  int bf = *flagp;
  int tid = threadIdx.x;
  for (int i = tid; i < H1 * TIN * FH; i += 256) w[i] = ldx(W1, i, bf);
  if (tid < H1) bb[tid] = ldx(b1, tid, bf);
  __syncthreads();
  int t = blockIdx.x >> 8;
  int n = ((blockIdx.x & 255) << 3) + (tid >> 5);
  int k = tid & 31;
  float acc = bb[k];
#pragma unroll
  for (int ti = 0; ti < TIN; ++ti) {
#pragma unroll
    for (int f = 0; f < FH; ++f) {
      acc += ldx(hist, (((t * FH + f) * NN + n) * TIN) + ti, bf) *
             w[k * (TIN * FH) + ti * FH + f];
    }
  }
  h1[((t * NN + n) * H1) + k] = (acc > 0.f) ? acc : expm1f(acc);
}

// ---------------------------------------------------------------- LSTM
__global__ __launch_bounds__(256, 1) void k_lstm(
    const float* __restrict__ h1, cvp W_ih, cvp W_hh, cvp b_ih, cvp b_hh,
    float* __restrict__ hs, const int* __restrict__ flagp) {
  __shared__ float4 wih[H1 * 64];
  __shared__ float4 whh[H2 * 64];
  __shared__ float4 bsum[64];
  __shared__ float xbuf[4][2][H1];
  __shared__ float hbuf[4][2][H2];
  int bf = *flagp;
  int tid = threadIdx.x;
  for (int idx = tid; idx < 256 * H1; idx += 256) {
    int r = idx >> 5, k = idx & 31;
    ((float*)wih)[(((k << 6) + (r & 63)) << 2) + (r >> 6)] = ldx(W_ih, idx, bf);
  }
  for (int idx = tid; idx < 256 * H2; idx += 256) {
    int r = idx >> 6, k = idx & 63;
    ((float*)whh)[(((k << 6) + (r & 63)) << 2) + (r >> 6)] = ldx(W_hh, idx, bf);
  }
  {
    int r = tid;
    ((float*)bsum)[((r & 63) << 2) + (r >> 6)] = ldx(b_ih, r, bf) + ldx(b_hh, r, bf);
  }
  int wave = tid >> 6, lane = tid & 63;
  int na = (blockIdx.x << 3) + (wave << 1);
  hbuf[wave][0][lane] = 0.f;
  hbuf[wave][1][lane] = 0.f;
  __syncthreads();
  float4 bs = bsum[lane];
  float c0 = 0.f, c1 = 0.f;
  for (int t = 0; t < BB; ++t) {
    {
      int which = lane >> 5, li = lane & 31;
      xbuf[wave][which][li] = h1[((t * NN + na + which) * H1) + li];
    }
    __syncthreads();
    float ai0 = bs.x, af0 = bs.y, ag0 = bs.z, ao0 = bs.w;
    float ai1 = bs.x, af1 = bs.y, ag1 = bs.z, ao1 = bs.w;
#pragma unroll
    for (int k = 0; k < H1; ++k) {
      float4 wv = wih[(k << 6) + lane];
      float xa = xbuf[wave][0][k], xb = xbuf[wave][1][k];
      ai0 += wv.x * xa; af0 += wv.y * xa; ag0 += wv.z * xa; ao0 += wv.w * xa;
      ai1 += wv.x * xb; af1 += wv.y * xb; ag1 += wv.z * xb; ao1 += wv.w * xb;
    }
#pragma unroll
    for (int k = 0; k < H2; ++k) {
      float4 wv = whh[(k << 6) + lane];
      float ha = hbuf[wave][0][k], hb = hbuf[wave][1][k];
      ai0 += wv.x * ha; af0 += wv.y * ha; ag0 += wv.z * ha; ao0 += wv.w * ha;
      ai1 += wv.x * hb; af1 += wv.y * hb; ag1 += wv.z * hb; ao1 += wv.w * hb;
    }
    float h0v, h1v;
    {
      float si = 1.f / (1.f + __expf(-ai0));
      float sf = 1.f / (1.f + __expf(-af0));
      float so = 1.f / (1.f + __expf(-ao0));
      float tg = tanhf(ag0);
      c0 = sf * c0 + si * tg;
      h0v = so * tanhf(c0);
    }
    {
      float si = 1.f / (1.f + __expf(-ai1));
      float sf = 1.f / (1.f + __expf(-af1));
      float so = 1.f / (1.f + __expf(-ao1));
      float tg = tanhf(ag1);
      c1 = sf * c1 + si * tg;
      h1v = so * tanhf(c1);
    }
    __syncthreads();
    hbuf[wave][0][lane] = h0v;
    hbuf[wave][1][lane] = h1v;
    hs[((t * NN + na) * H2) + lane] = h0v;
    hs[((t * NN + na + 1) * H2) + lane] = h1v;
    __syncthreads();
  }
}

// ---------------------------------------------------------------- gatprep:
// Wh = hs@Wg; sv/dv projections; emit WhFr = Wh in bf16 MFMA B-frag order:
// WhFr[((b*64+ks)*4+nt)*64+lane] = short8 of Wh[b][ks*32+(lane>>4)*8+j][nt*16+(lane&15)]
__global__ __launch_bounds__(256) void k_gatprep(
    const float* __restrict__ hs, cvp Wg, cvp a_src, cvp a_dst,
    __hip_bfloat16* __restrict__ WhFr, float* __restrict__ sv,
    float* __restrict__ dv, const int* __restrict__ flagp) {
  __shared__ float wg[H2 * H2];        // 16 KB
  __shared__ float tile[32][H2 + 1];   // ~8.1 KB, padded
  int bf = *flagp;
  int tid = threadIdx.x;
  for (int i = tid; i < H2 * H2; i += 256) wg[i] = ldx(Wg, i, bf);
  __syncthreads();
  int wave = tid >> 6, lane = tid & 63;
  int b = blockIdx.x >> 6;
  int jt = blockIdx.x & 63;
  int j0 = jt << 5;
  float as = ldx(a_src, lane, bf);
  float ad = ldx(a_dst, lane, bf);
#pragma unroll
  for (int rr = 0; rr < 8; ++rr) {
    int jl = (wave << 3) + rr;
    int row = b * NN + j0 + jl;
    float hreg = hs[row * H2 + lane];
    float acc = 0.f;
#pragma unroll
    for (int k = 0; k < H2; ++k)
      acc += __shfl(hreg, k, 64) * wg[(k << 6) + lane];
    tile[jl][lane] = acc;
    float s = acc * as, d = acc * ad;
#pragma unroll
    for (int off = 32; off > 0; off >>= 1) {
      s += __shfl_xor(s, off, 64);
      d += __shfl_xor(d, off, 64);
    }
    if (lane == 0) { sv[row] = s; dv[row] = d; }
  }
  __syncthreads();
  // frag repack
  int nt = tid >> 6, l = tid & 63;
  int q = l >> 4, m = l & 15;
  float v[8];
#pragma unroll
  for (int jj = 0; jj < 8; ++jj)
    v[jj] = tile[(q << 3) + jj][(nt << 4) + m];
  short8 fr;
#pragma unroll
  for (int p = 0; p < 4; ++p)
    ((__hip_bfloat162*)&fr)[p] =
        __float22bfloat162_rn(make_float2(v[2 * p], v[2 * p + 1]));
  size_t off = ((size_t)(b * 64 + jt) * 4 + nt) * 64 + l;
  ((short8*)WhFr)[off] = fr;
}

// ---------------------------------------------------------------- GAT flash+MFMA
struct Stage {
  int4 a0, a1;
  float4 d0, d1;
  short8 b0, b1, b2, b3;
};

__device__ __forceinline__ Stage ld_stage(const int* arow, const float* drow,
                                          const short8* wf, int ks, int k0, int lane) {
  Stage s;
  int kb = ks * 32 + k0;
  s.a0 = *(const int4*)(arow + kb);
  s.a1 = *(const int4*)(arow + kb + 4);
  s.d0 = *(const float4*)(drow + kb);
  s.d1 = *(const float4*)(drow + kb + 4);
  const short8* base = wf + (size_t)ks * 256 + lane;
  s.b0 = base[0];
  s.b1 = base[64];
  s.b2 = base[128];
  s.b3 = base[192];
  return s;
}

__global__ __launch_bounds__(64) void k_gat(
    const int* __restrict__ adj, const __hip_bfloat16* __restrict__ WhFr,
    const float* __restrict__ sv, const float* __restrict__ dv,
    void* __restrict__ out, const int* __restrict__ flagp) {
  int bf = *flagp;
  int lane = threadIdx.x;
  int b = blockIdx.x >> 7;
  int i0 = (blockIdx.x & 127) << 4;
  int q = lane >> 4, m = lane & 15;
  int i = i0 + m;
  float sva = sv[b * NN + i];
  const int* arow = adj + ((size_t)(b * 2 + 1) * NN + i) * NN;
  const float* drow = dv + b * NN;
  const short8* wf = ((const short8*)WhFr) + (size_t)b * 64 * 256;
  floatx4 acc0 = {0.f, 0.f, 0.f, 0.f};
  floatx4 acc1 = acc0, acc2 = acc0, acc3 = acc0;
  float S = 0.f;
  int k0 = q << 3;

  Stage s0 = ld_stage(arow, drow, wf, 0, k0, lane);
  Stage s1 = ld_stage(arow, drow, wf, 1, k0, lane);
#pragma unroll 2
  for (int ks = 0; ks < 64; ++ks) {
    int ksn = (ks + 2 < 64) ? ks + 2 : 63;
    Stage nx = ld_stage(arow, drow, wf, ksn, k0, lane);
    int av[8] = {s0.a0.x, s0.a0.y, s0.a0.z, s0.a0.w,
                 s0.a1.x, s0.a1.y, s0.a1.z, s0.a1.w};
    float dd[8] = {s0.d0.x, s0.d0.y, s0.d0.z, s0.d0.w,
                   s0.d1.x, s0.d1.y, s0.d1.z, s0.d1.w};
    float pv[8];
#pragma unroll
    for (int jj = 0; jj < 8; ++jj) {
      float t = sva + dd[jj];
      float e = __expf(fmaxf(t, 0.2f * t));   // exp(leaky_relu(t))
      float p = (av[jj] != 0) ? e : 0.f;
      pv[jj] = p;
      S += p;
    }
    short8 afr;
#pragma unroll
    for (int p2 = 0; p2 < 4; ++p2)
      ((__hip_bfloat162*)&afr)[p2] =
          __float22bfloat162_rn(make_float2(pv[2 * p2], pv[2 * p2 + 1]));
    acc0 = __builtin_amdgcn_mfma_f32_16x16x32_bf16(afr, s0.b0, acc0, 0, 0, 0);
    acc1 = __builtin_amdgcn_mfma_f32_16x16x32_bf16(afr, s0.b1, acc1, 0, 0, 0);
    acc2 = __builtin_amdgcn_mfma_f32_16x16x32_bf16(afr, s0.b2, acc2, 0, 0, 0);
    acc3 = __builtin_amdgcn_mfma_f32_16x16x32_bf16(afr, s0.b3, acc3, 0, 0, 0);
    s0 = s1;
    s1 = nx;
  }
  // total S per row m (sum across the 4 k-quads)
  S += __shfl_xor(S, 16, 64);
  S += __shfl_xor(S, 32, 64);
  float inv = 1.f / S;
  float ivr[4];
#pragma unroll
  for (int r = 0; r < 4; ++r) ivr[r] = __shfl(inv, (q << 2) + r, 64);

  floatx4 accs[4] = {acc0, acc1, acc2, acc3};
  if (bf) {
    __hip_bfloat16* o = (__hip_bfloat16*)out;
#pragma unroll
    for (int nt = 0; nt < 4; ++nt) {
#pragma unroll
      for (int r = 0; r < 4; ++r) {
        float v = accs[nt][r] * ivr[r];
        v = (v > 0.f) ? v : expm1f(v);
        int row = i0 + (q << 2) + r;
        o[((size_t)b * NN + row) * H2 + (nt << 4) + m] = __float2bfloat16(v);
      }
    }
  } else {
    float* o = (float*)out;
#pragma unroll
    for (int nt = 0; nt < 4; ++nt) {
#pragma unroll
      for (int r = 0; r < 4; ++r) {
        float v = accs[nt][r] * ivr[r];
        v = (v > 0.f) ? v : expm1f(v);
        int row = i0 + (q << 2) + r;
        o[((size_t)b * NN + row) * H2 + (nt << 4) + m] = v;
      }
    }
  }
}

// ---------------------------------------------------------------- launch
extern "C" void kernel_launch(void* const* d_in, const int* in_sizes, int n_in,
                              void* d_out, int out_size, void* d_ws, size_t ws_size,
                              hipStream_t stream) {
  (void)in_sizes; (void)n_in; (void)out_size; (void)ws_size;
  cvp hist  = d_in[0];
  const int* adj = (const int*)d_in[1];
  cvp W1    = d_in[2];
  cvp b1    = d_in[3];
  cvp W_ih  = d_in[4];
  cvp W_hh  = d_in[5];
  cvp b_ih  = d_in[6];
  cvp b_hh  = d_in[7];
  cvp Wg    = d_in[8];
  cvp a_src = d_in[9];
  cvp a_dst = d_in[10];

  float* ws  = (float*)d_ws;
  float* h1  = ws;                                   // 524288 f
  float* hs  = h1 + BB * NN * H1;                    // 1048576 f
  __hip_bfloat16* WhFr = (__hip_bfloat16*)(hs + BB * NN * H2);  // 2 MB (524288 f slots)
  float* sv  = hs + BB * NN * H2 + 524288;           // 16384 f
  float* dv  = sv + BB * NN;                         // 16384 f
  int* flag  = (int*)(dv + BB * NN);

  k_detect<<<1, 256, 0, stream>>>((const unsigned int*)W_ih, flag);
  k_h1<<<2048, 256, 0, stream>>>(hist, W1, b1, h1, flag);
  k_lstm<<<256, 256, 0, stream>>>(h1, W_ih, W_hh, b_ih, b_hh, hs, flag);
  k_gatprep<<<512, 256, 0, stream>>>(hs, Wg, a_src, a_dst, WhFr, sv, dv, flag);
  k_gat<<<1024, 64, 0, stream>>>(adj, WhFr, sv, dv, d_out, flag);
}

// Round 3
// 432.654 us; speedup vs baseline: 1.9638x; 1.3482x over previous
//
#include <hip/hip_runtime.h>
#include <hip/hip_bf16.h>
#include <math.h>

#define BB 8
#define FH 8
#define NN 2048
#define TIN 5
#define H1 32
#define H2 64

typedef const void* cvp;
typedef __attribute__((ext_vector_type(8))) short short8;
typedef __attribute__((ext_vector_type(4))) float floatx4;

__device__ __forceinline__ float ldx(cvp p, int i, int bf) {
  if (bf) return __bfloat162float(((const __hip_bfloat16*)p)[i]);
  return ((const float*)p)[i];
}

// load 4 consecutive values (i % 4 == 0) from fp32 or bf16 source
__device__ __forceinline__ float4 ld4(cvp p, int i, int bf) {
  if (bf) {
    const __hip_bfloat162* q = (const __hip_bfloat162*)p;
    float2 a = __bfloat1622float2(q[(i >> 1)]);
    float2 b = __bfloat1622float2(q[(i >> 1) + 1]);
    return make_float4(a.x, a.y, b.x, b.y);
  }
  return ((const float4*)p)[i >> 2];
}

__device__ __forceinline__ float sigf(float x) {
  return 1.f / (1.f + __expf(-x));
}

// ---------------------------------------------------------------- detector
__global__ void k_detect(const unsigned int* __restrict__ w, int* __restrict__ flag) {
  __shared__ int cnt;
  if (threadIdx.x == 0) cnt = 0;
  __syncthreads();
  int local = 0;
  for (int i = threadIdx.x; i < 1024; i += 256) {
    unsigned e = (w[i] >> 7) & 0xFFu;
    local += (e >= 100u && e <= 150u) ? 1 : 0;
  }
  atomicAdd(&cnt, local);
  __syncthreads();
  if (threadIdx.x == 0) *flag = (cnt > 700) ? 1 : 0;
}

// ---------------------------------------------------------------- h1 = elu(x @ W1^T + b1)
__global__ void k_h1(cvp hist, cvp W1, cvp b1, float* __restrict__ h1,
                     const int* __restrict__ flagp) {
  __shared__ float w[H1 * TIN * FH];
  __shared__ float bb[H1];
  int bf = *flagp;
  int tid = threadIdx.x;
  for (int i = tid; i < H1 * TIN * FH; i += 256) w[i] = ldx(W1, i, bf);
  if (tid < H1) bb[tid] = ldx(b1, tid, bf);
  __syncthreads();
  int t = blockIdx.x >> 8;
  int n = ((blockIdx.x & 255) << 3) + (tid >> 5);
  int k = tid & 31;
  float acc = bb[k];
#pragma unroll
  for (int ti = 0; ti < TIN; ++ti) {
#pragma unroll
    for (int f = 0; f < FH; ++f) {
      acc += ldx(hist, (((t * FH + f) * NN + n) * TIN) + ti, bf) *
             w[k * (TIN * FH) + ti * FH + f];
    }
  }
  h1[((t * NN + n) * H1) + k] = (acc > 0.f) ? acc : expm1f(acc);
}

// ---------------------------------------------------------------- LSTM
// Block = 4 waves, 4 nodes. Wave w owns gate-type w (rows [w*64, w*64+64)).
// Lane l keeps its gate row's 96 weights (W_ih 32 + W_hh 64) in REGISTERS.
// Per step: x||h in LDS (float4 same-address broadcasts), 4 accs per lane
// (one per node). Gate nonlinearity through a small LDS gate buffer; c-state
// is one persistent register per thread (thread t owns node t>>6, h-idx t&63).
__global__ __launch_bounds__(256, 2) void k_lstm(
    const float* __restrict__ h1, cvp W_ih, cvp W_hh, cvp b_ih, cvp b_hh,
    float* __restrict__ hs, const int* __restrict__ flagp) {
  __shared__ __align__(16) float xh[4][96];   // per node: x[0..31], h[32..95]
  __shared__ float gbuf[4][256];              // gates per node
  int bf = *flagp;
  int tid = threadIdx.x;
  int w = tid >> 6, lane = tid & 63;
  int g = (w << 6) + lane;                    // global gate row
  int n0 = blockIdx.x << 2;                   // first node of this block
  int node_w = n0 + w;                        // node this thread's epilogue owns

  float wreg[96];
#pragma unroll
  for (int kq = 0; kq < 8; ++kq) {
    float4 v = ld4(W_ih, g * 32 + (kq << 2), bf);
    wreg[(kq << 2) + 0] = v.x; wreg[(kq << 2) + 1] = v.y;
    wreg[(kq << 2) + 2] = v.z; wreg[(kq << 2) + 3] = v.w;
  }
#pragma unroll
  for (int kq = 0; kq < 16; ++kq) {
    float4 v = ld4(W_hh, g * 64 + (kq << 2), bf);
    wreg[32 + (kq << 2) + 0] = v.x; wreg[32 + (kq << 2) + 1] = v.y;
    wreg[32 + (kq << 2) + 2] = v.z; wreg[32 + (kq << 2) + 3] = v.w;
  }
  float bias = ldx(b_ih, g, bf) + ldx(b_hh, g, bf);

  // init h(0) = 0
  xh[w][32 + lane] = 0.f;
  float c = 0.f;

  for (int t = 0; t < BB; ++t) {
    if (lane < 32) xh[w][lane] = h1[((t * NN + node_w) * H1) + lane];
    __syncthreads();
    float acc[4] = {bias, bias, bias, bias};
    const float4* xq0 = (const float4*)xh[0];
    const float4* xq1 = (const float4*)xh[1];
    const float4* xq2 = (const float4*)xh[2];
    const float4* xq3 = (const float4*)xh[3];
#pragma unroll
    for (int kq = 0; kq < 24; ++kq) {
      float w0 = wreg[(kq << 2) + 0], w1 = wreg[(kq << 2) + 1];
      float w2 = wreg[(kq << 2) + 2], w3 = wreg[(kq << 2) + 3];
      float4 v0 = xq0[kq], v1 = xq1[kq], v2 = xq2[kq], v3 = xq3[kq];
      acc[0] += w0 * v0.x + w1 * v0.y + w2 * v0.z + w3 * v0.w;
      acc[1] += w0 * v1.x + w1 * v1.y + w2 * v1.z + w3 * v1.w;
      acc[2] += w0 * v2.x + w1 * v2.y + w2 * v2.z + w3 * v2.w;
      acc[3] += w0 * v3.x + w1 * v3.y + w2 * v3.z + w3 * v3.w;
    }
#pragma unroll
    for (int nd = 0; nd < 4; ++nd) gbuf[nd][g] = acc[nd];
    __syncthreads();
    // epilogue: thread owns (node = w, j = lane)
    float gi = gbuf[w][lane];
    float gf = gbuf[w][64 + lane];
    float gg = gbuf[w][128 + lane];
    float go = gbuf[w][192 + lane];
    c = sigf(gf) * c + sigf(gi) * tanhf(gg);
    float h = sigf(go) * tanhf(c);
    xh[w][32 + lane] = h;
    hs[((t * NN + node_w) * H2) + lane] = h;
    __syncthreads();
  }
}

// ---------------------------------------------------------------- gatprep:
// Wh = hs@Wg; sv/dv projections; emit WhFr = Wh in bf16 MFMA B-frag order
__global__ __launch_bounds__(256) void k_gatprep(
    const float* __restrict__ hs, cvp Wg, cvp a_src, cvp a_dst,
    __hip_bfloat16* __restrict__ WhFr, float* __restrict__ sv,
    float* __restrict__ dv, const int* __restrict__ flagp) {
  __shared__ float wg[H2 * H2];
  __shared__ float tile[32][H2 + 1];
  int bf = *flagp;
  int tid = threadIdx.x;
  for (int i = tid; i < H2 * H2; i += 256) wg[i] = ldx(Wg, i, bf);
  __syncthreads();
  int wave = tid >> 6, lane = tid & 63;
  int b = blockIdx.x >> 6;
  int jt = blockIdx.x & 63;
  int j0 = jt << 5;
  float as = ldx(a_src, lane, bf);
  float ad = ldx(a_dst, lane, bf);
#pragma unroll
  for (int rr = 0; rr < 8; ++rr) {
    int jl = (wave << 3) + rr;
    int row = b * NN + j0 + jl;
    float hreg = hs[row * H2 + lane];
    float acc = 0.f;
#pragma unroll
    for (int k = 0; k < H2; ++k)
      acc += __shfl(hreg, k, 64) * wg[(k << 6) + lane];
    tile[jl][lane] = acc;
    float s = acc * as, d = acc * ad;
#pragma unroll
    for (int off = 32; off > 0; off >>= 1) {
      s += __shfl_xor(s, off, 64);
      d += __shfl_xor(d, off, 64);
    }
    if (lane == 0) { sv[row] = s; dv[row] = d; }
  }
  __syncthreads();
  int nt = tid >> 6, l = tid & 63;
  int q = l >> 4, m = l & 15;
  float v[8];
#pragma unroll
  for (int jj = 0; jj < 8; ++jj)
    v[jj] = tile[(q << 3) + jj][(nt << 4) + m];
  short8 fr;
#pragma unroll
  for (int p = 0; p < 4; ++p)
    ((__hip_bfloat162*)&fr)[p] =
        __float22bfloat162_rn(make_float2(v[2 * p], v[2 * p + 1]));
  size_t off = ((size_t)(b * 64 + jt) * 4 + nt) * 64 + l;
  ((short8*)WhFr)[off] = fr;
}

// ---------------------------------------------------------------- GAT flash+MFMA
struct Stage {
  int4 a0, a1;
  float4 d0, d1;
  short8 b0, b1, b2, b3;
};

__device__ __forceinline__ Stage ld_stage(const int* arow, const float* drow,
                                          const short8* wf, int ks, int k0, int lane) {
  Stage s;
  int kb = ks * 32 + k0;
  s.a0 = *(const int4*)(arow + kb);
  s.a1 = *(const int4*)(arow + kb + 4);
  s.d0 = *(const float4*)(drow + kb);
  s.d1 = *(const float4*)(drow + kb + 4);
  const short8* base = wf + (size_t)ks * 256 + lane;
  s.b0 = base[0];
  s.b1 = base[64];
  s.b2 = base[128];
  s.b3 = base[192];
  return s;
}

// Block = 4 waves over one 16-row i-tile; wave w covers K-steps [w*16, w*16+16).
// Partial accs + partial softmax sums combined through LDS; wave 0 epilogues.
__global__ __launch_bounds__(256, 3) void k_gat(
    const int* __restrict__ adj, const __hip_bfloat16* __restrict__ WhFr,
    const float* __restrict__ sv, const float* __restrict__ dv,
    void* __restrict__ out, const int* __restrict__ flagp) {
  __shared__ floatx4 abuf[3][4][64];   // 12 KB: waves 1..3 partial accs
  __shared__ float sbuf[3][64];
  int bf = *flagp;
  int tid = threadIdx.x;
  int w = tid >> 6, lane = tid & 63;
  int b = blockIdx.x >> 7;
  int i0 = (blockIdx.x & 127) << 4;
  int q = lane >> 4, m = lane & 15;
  int i = i0 + m;
  float sva = sv[b * NN + i];
  const int* arow = adj + ((size_t)(b * 2 + 1) * NN + i) * NN;
  const float* drow = dv + b * NN;
  const short8* wf = ((const short8*)WhFr) + (size_t)b * 64 * 256;
  floatx4 acc0 = {0.f, 0.f, 0.f, 0.f};
  floatx4 acc1 = acc0, acc2 = acc0, acc3 = acc0;
  float S = 0.f;
  int k0 = q << 3;
  int ksb = w << 4;

  Stage s0 = ld_stage(arow, drow, wf, ksb + 0, k0, lane);
  Stage s1 = ld_stage(arow, drow, wf, ksb + 1, k0, lane);
#pragma unroll 2
  for (int ks = 0; ks < 16; ++ks) {
    int ksn = ksb + ((ks + 2 < 16) ? ks + 2 : 15);
    Stage nx = ld_stage(arow, drow, wf, ksn, k0, lane);
    int av[8] = {s0.a0.x, s0.a0.y, s0.a0.z, s0.a0.w,
                 s0.a1.x, s0.a1.y, s0.a1.z, s0.a1.w};
    float dd[8] = {s0.d0.x, s0.d0.y, s0.d0.z, s0.d0.w,
                   s0.d1.x, s0.d1.y, s0.d1.z, s0.d1.w};
    float pv[8];
#pragma unroll
    for (int jj = 0; jj < 8; ++jj) {
      float t = sva + dd[jj];
      float e = __expf(fmaxf(t, 0.2f * t));   // exp(leaky_relu(t))
      float p = (av[jj] != 0) ? e : 0.f;
      pv[jj] = p;
      S += p;
    }
    short8 afr;
#pragma unroll
    for (int p2 = 0; p2 < 4; ++p2)
      ((__hip_bfloat162*)&afr)[p2] =
          __float22bfloat162_rn(make_float2(pv[2 * p2], pv[2 * p2 + 1]));
    acc0 = __builtin_amdgcn_mfma_f32_16x16x32_bf16(afr, s0.b0, acc0, 0, 0, 0);
    acc1 = __builtin_amdgcn_mfma_f32_16x16x32_bf16(afr, s0.b1, acc1, 0, 0, 0);
    acc2 = __builtin_amdgcn_mfma_f32_16x16x32_bf16(afr, s0.b2, acc2, 0, 0, 0);
    acc3 = __builtin_amdgcn_mfma_f32_16x16x32_bf16(afr, s0.b3, acc3, 0, 0, 0);
    s0 = s1;
    s1 = nx;
  }
  // within-wave: sum S across the 4 q-groups -> per-row partial
  S += __shfl_xor(S, 16, 64);
  S += __shfl_xor(S, 32, 64);
  if (w > 0) {
    abuf[w - 1][0][lane] = acc0;
    abuf[w - 1][1][lane] = acc1;
    abuf[w - 1][2][lane] = acc2;
    abuf[w - 1][3][lane] = acc3;
    sbuf[w - 1][lane] = S;
  }
  __syncthreads();
  if (w != 0) return;
#pragma unroll
  for (int ww = 0; ww < 3; ++ww) {
    acc0 += abuf[ww][0][lane];
    acc1 += abuf[ww][1][lane];
    acc2 += abuf[ww][2][lane];
    acc3 += abuf[ww][3][lane];
    S += sbuf[ww][lane];
  }
  float inv = 1.f / S;
  float ivr[4];
#pragma unroll
  for (int r = 0; r < 4; ++r) ivr[r] = __shfl(inv, (q << 2) + r, 64);

  floatx4 accs[4] = {acc0, acc1, acc2, acc3};
  if (bf) {
    __hip_bfloat16* o = (__hip_bfloat16*)out;
#pragma unroll
    for (int nt = 0; nt < 4; ++nt) {
#pragma unroll
      for (int r = 0; r < 4; ++r) {
        float v = accs[nt][r] * ivr[r];
        v = (v > 0.f) ? v : expm1f(v);
        int row = i0 + (q << 2) + r;
        o[((size_t)b * NN + row) * H2 + (nt << 4) + m] = __float2bfloat16(v);
      }
    }
  } else {
    float* o = (float*)out;
#pragma unroll
    for (int nt = 0; nt < 4; ++nt) {
#pragma unroll
      for (int r = 0; r < 4; ++r) {
        float v = accs[nt][r] * ivr[r];
        v = (v > 0.f) ? v : expm1f(v);
        int row = i0 + (q << 2) + r;
        o[((size_t)b * NN + row) * H2 + (nt << 4) + m] = v;
      }
    }
  }
}

// ---------------------------------------------------------------- launch
extern "C" void kernel_launch(void* const* d_in, const int* in_sizes, int n_in,
                              void* d_out, int out_size, void* d_ws, size_t ws_size,
                              hipStream_t stream) {
  (void)in_sizes; (void)n_in; (void)out_size; (void)ws_size;
  cvp hist  = d_in[0];
  const int* adj = (const int*)d_in[1];
  cvp W1    = d_in[2];
  cvp b1    = d_in[3];
  cvp W_ih  = d_in[4];
  cvp W_hh  = d_in[5];
  cvp b_ih  = d_in[6];
  cvp b_hh  = d_in[7];
  cvp Wg    = d_in[8];
  cvp a_src = d_in[9];
  cvp a_dst = d_in[10];

  float* ws  = (float*)d_ws;
  float* h1  = ws;                                   // 524288 f
  float* hs  = h1 + BB * NN * H1;                    // 1048576 f
  __hip_bfloat16* WhFr = (__hip_bfloat16*)(hs + BB * NN * H2);  // 2 MB
  float* sv  = hs + BB * NN * H2 + 524288;           // 16384 f
  float* dv  = sv + BB * NN;                         // 16384 f
  int* flag  = (int*)(dv + BB * NN);

  k_detect<<<1, 256, 0, stream>>>((const unsigned int*)W_ih, flag);
  k_h1<<<2048, 256, 0, stream>>>(hist, W1, b1, h1, flag);
  k_lstm<<<512, 256, 0, stream>>>(h1, W_ih, W_hh, b_ih, b_hh, hs, flag);
  k_gatprep<<<512, 256, 0, stream>>>(hs, Wg, a_src, a_dst, WhFr, sv, dv, flag);
  k_gat<<<1024, 256, 0, stream>>>(adj, WhFr, sv, dv, d_out, flag);
}